// Round 1
// baseline (982.784 us; speedup 1.0000x reference)
//
#include <hip/hip_runtime.h>

// ComHG graph attention: N=50000 nodes, E=1.6M edges, DIN=128, DOUT=256, DA=32
// Pipeline:
//   K1 proj:    a_row = x@W_row * rsqrt(DA), a_col = x@W_col        [N,32] each
//   K2 edge:    p[e] = exp(leaky(dot(a_row[row],a_col[col]))), deg[row] += p
//               (global-max shift dropped: cancels in p/deg up to 1e-15 eps)
//   K3 scatter: feat[row] += (0.5*adj + 0.5*p/deg) * x[col]         [N,128]
//   K4 gemm:    out = feat @ W_x + b_x                              [N,256]

#define DIN   128
#define DOUT  256
#define DA    32
#define SLOPE 0.2f
#define RSQRT_DA 0.17677669529663687f   // 1/sqrt(32)

// ---------------- K1: per-node attention projections ----------------
// block = 256 threads -> 8 nodes/block, 32 threads (one per da) per node.
__global__ __launch_bounds__(256) void proj_kernel(
    const float* __restrict__ x, const float* __restrict__ Wr,
    const float* __restrict__ Wc, float* __restrict__ a_row,
    float* __restrict__ a_col) {
  __shared__ float sWr[DIN][DA];   // 16 KB
  __shared__ float sWc[DIN][DA];   // 16 KB
  __shared__ float sx[8][DIN];     //  4 KB
  const int t = threadIdx.x;
  // Stage W_row / W_col (4096 floats each) as float4, coalesced.
  {
    const float4* wr4 = (const float4*)Wr;
    const float4* wc4 = (const float4*)Wc;
    float4* sr4 = (float4*)sWr;
    float4* sc4 = (float4*)sWc;
#pragma unroll
    for (int i = 0; i < 4; ++i) {
      sr4[t + 256 * i] = wr4[t + 256 * i];
      sc4[t + 256 * i] = wc4[t + 256 * i];
    }
  }
  // Stage 8 node rows of x (1024 floats).
  const int node0 = blockIdx.x * 8;
  {
    const float4* xg = (const float4*)(x + (size_t)node0 * DIN);
    ((float4*)sx)[t] = xg[t];
  }
  __syncthreads();

  const int node = t >> 5;    // 0..7
  const int da = t & 31;      // 0..31
  float ar = 0.f, ac = 0.f;
#pragma unroll
  for (int k = 0; k < DIN; ++k) {
    const float xv = sx[node][k];        // broadcast (same addr per 32 lanes)
    ar += xv * sWr[k][da];               // stride-1 across lanes: conflict-free
    ac += xv * sWc[k][da];
  }
  const int g = (node0 + node) * DA + da;
  a_row[g] = ar * RSQRT_DA;              // fold rsqrt(DA) into one side
  a_col[g] = ac;
}

// ---------------- K2: edge logits -> exp -> degree atomic ----------------
__global__ __launch_bounds__(256) void edge_logit_kernel(
    const float* __restrict__ a_row, const float* __restrict__ a_col,
    const int* __restrict__ row, const int* __restrict__ col,
    float* __restrict__ p, float* __restrict__ deg, int E) {
  const int e = blockIdx.x * 256 + threadIdx.x;
  if (e >= E) return;
  const int r = row[e];
  const int c = col[e];
  const float4* ar = (const float4*)(a_row + (size_t)r * DA);
  const float4* ac = (const float4*)(a_col + (size_t)c * DA);
  float dot = 0.f;
#pragma unroll
  for (int i = 0; i < DA / 4; ++i) {
    const float4 u = ar[i];
    const float4 v = ac[i];
    dot += u.x * v.x + u.y * v.y + u.z * v.z + u.w * v.w;
  }
  const float l = (dot >= 0.f) ? dot : SLOPE * dot;
  const float pe = __expf(l);
  p[e] = pe;
  atomicAdd(deg + r, pe);
}

// ---------------- K3: scatter SpMM into feat ----------------
// 128 threads per edge (one per input dim); 2 edges per 256-thread block.
__global__ __launch_bounds__(256) void scatter_kernel(
    const float* __restrict__ x, const int* __restrict__ row,
    const int* __restrict__ col, const float* __restrict__ adj,
    const float* __restrict__ p, const float* __restrict__ deg,
    float* __restrict__ feat, int E) {
  const int idx = blockIdx.x * 256 + threadIdx.x;  // E*128 = 204.8M < 2^31
  const int e = idx >> 7;
  const int d = idx & 127;
  if (e >= E) return;
  const int r = row[e];   // same addr across 128-thread group: coalesces
  const int c = col[e];
  const float val = 0.5f * adj[e] + 0.5f * p[e] / (deg[r] + 1e-15f);
  atomicAdd(feat + (size_t)r * DIN + d, val * x[(size_t)c * DIN + d]);
}

// ---------------- K4: dense GEMM out = feat @ W_x + b ----------------
// block = 256 threads (one per output col), 16 rows per block.
__global__ __launch_bounds__(256) void gemm_kernel(
    const float* __restrict__ feat, const float* __restrict__ Wx,
    const float* __restrict__ bx, float* __restrict__ out) {
  __shared__ float fs[16][DIN];   // 8 KB
  const int t = threadIdx.x;
  const int row0 = blockIdx.x * 16;
  {
    const float4* fg = (const float4*)(feat + (size_t)row0 * DIN);
    float4* fs4 = (float4*)fs;
    fs4[t] = fg[t];
    fs4[t + 256] = fg[t + 256];
  }
  __syncthreads();

  float acc[16];
#pragma unroll
  for (int r = 0; r < 16; ++r) acc[r] = 0.f;

  for (int k = 0; k < DIN; k += 4) {
    const float w0 = Wx[(k + 0) * DOUT + t];
    const float w1 = Wx[(k + 1) * DOUT + t];
    const float w2 = Wx[(k + 2) * DOUT + t];
    const float w3 = Wx[(k + 3) * DOUT + t];
#pragma unroll
    for (int r = 0; r < 16; ++r) {
      const float4 f = *(const float4*)&fs[r][k];  // b128 broadcast, no conflict
      acc[r] += f.x * w0 + f.y * w1 + f.z * w2 + f.w * w3;
    }
  }

  const float b = bx[t];
#pragma unroll
  for (int r = 0; r < 16; ++r)
    out[(size_t)(row0 + r) * DOUT + t] = acc[r] + b;
}

extern "C" void kernel_launch(void* const* d_in, const int* in_sizes, int n_in,
                              void* d_out, int out_size, void* d_ws, size_t ws_size,
                              hipStream_t stream) {
  const float* x   = (const float*)d_in[0];
  const int*   row = (const int*)d_in[1];
  const int*   col = (const int*)d_in[2];
  const float* adj = (const float*)d_in[3];
  const float* Wr  = (const float*)d_in[4];
  const float* Wc  = (const float*)d_in[5];
  const float* Wx  = (const float*)d_in[6];
  const float* bx  = (const float*)d_in[7];
  float* out = (float*)d_out;

  const int n = in_sizes[0] / DIN;   // 50000
  const int E = in_sizes[1];         // 1600000

  // Workspace layout (floats): a_row[n*32] a_col[n*32] p[E] deg[n_pad] feat[n*128]
  float* a_row = (float*)d_ws;
  float* a_col = a_row + (size_t)n * DA;
  float* p     = a_col + (size_t)n * DA;
  float* deg   = p + E;
  const int n_pad = (n + 63) & ~63;
  float* feat  = deg + n_pad;
  // Total: 3*1.6M + 50048 + 6.4M floats ~= 45 MB

  // Zero the accumulated regions (deg + feat); ws is poisoned 0xAA each call.
  hipMemsetAsync(deg, 0, ((size_t)n_pad + (size_t)n * DIN) * sizeof(float), stream);

  proj_kernel<<<n / 8, 256, 0, stream>>>(x, Wr, Wc, a_row, a_col);
  edge_logit_kernel<<<(E + 255) / 256, 256, 0, stream>>>(a_row, a_col, row, col, p, deg, E);
  scatter_kernel<<<E / 2, 256, 0, stream>>>(x, row, col, adj, p, deg, feat, E);
  gemm_kernel<<<n / 16, 256, 0, stream>>>(feat, Wx, bx, out);
}

// Round 2
// 703.430 us; speedup vs baseline: 1.3971x; 1.3971x over previous
//
#include <hip/hip_runtime.h>

// ComHG graph attention: N=50000, E=1.6M, DIN=128, DOUT=256, DA=32
// Pipeline (CSR restructure to kill the 204.8M f32 atomics of round 1):
//   memset cnt
//   K1 proj:   a_row = x@W_row * rsqrt(DA), a_col = x@W_col          [N,32]
//   K2 hist:   cnt[row[e]]++                                          (int atomics)
//   K3 scan:   off = exclusive_prefix(cnt), wptr = copy               (1 block)
//   K4 sort:   pos = wptr[row[e]]++; scol[pos]=col[e]; sadj[pos]=adj[e]
//   K5 node:   per node i: p_e = exp(leaky(a_row[i]. a_col[c])), deg = sum p
//              feat[i][d] = sum_e (0.5*adj_e + 0.5*p_e/deg) * x[c_e][d]
//              (global-max shift dropped: cancels in p/deg up to 1e-15 eps)
//   K6 gemm:   out = feat @ W_x + b_x                                 [N,256]

#define DIN   128
#define DOUT  256
#define DA    32
#define SLOPE 0.2f
#define RSQRT_DA 0.17677669529663687f   // 1/sqrt(32)

// ---------------- K1: per-node attention projections ----------------
__global__ __launch_bounds__(256) void proj_kernel(
    const float* __restrict__ x, const float* __restrict__ Wr,
    const float* __restrict__ Wc, float* __restrict__ a_row,
    float* __restrict__ a_col) {
  __shared__ float sWr[DIN][DA];   // 16 KB
  __shared__ float sWc[DIN][DA];   // 16 KB
  __shared__ float sx[8][DIN];     //  4 KB
  const int t = threadIdx.x;
  {
    const float4* wr4 = (const float4*)Wr;
    const float4* wc4 = (const float4*)Wc;
    float4* sr4 = (float4*)sWr;
    float4* sc4 = (float4*)sWc;
#pragma unroll
    for (int i = 0; i < 4; ++i) {
      sr4[t + 256 * i] = wr4[t + 256 * i];
      sc4[t + 256 * i] = wc4[t + 256 * i];
    }
  }
  const int node0 = blockIdx.x * 8;
  {
    const float4* xg = (const float4*)(x + (size_t)node0 * DIN);
    ((float4*)sx)[t] = xg[t];
  }
  __syncthreads();

  const int node = t >> 5;
  const int da = t & 31;
  float ar = 0.f, ac = 0.f;
#pragma unroll
  for (int k = 0; k < DIN; ++k) {
    const float xv = sx[node][k];
    ar += xv * sWr[k][da];
    ac += xv * sWc[k][da];
  }
  const int g = (node0 + node) * DA + da;
  a_row[g] = ar * RSQRT_DA;
  a_col[g] = ac;
}

// ---------------- K2: degree histogram ----------------
__global__ __launch_bounds__(256) void hist_kernel(
    const int* __restrict__ row, int* __restrict__ cnt, int E) {
  const int e = blockIdx.x * 256 + threadIdx.x;
  if (e < E) atomicAdd(cnt + row[e], 1);
}

// ---------------- K3: single-block exclusive scan over n counters ----------------
__global__ __launch_bounds__(1024) void scan_kernel(
    const int* __restrict__ cnt, int* __restrict__ off,
    int* __restrict__ wptr, int n) {
  __shared__ int part[1024];
  const int t = threadIdx.x;
  const int chunk = (n + 1023) / 1024;
  const int base = t * chunk;
  int s = 0;
  for (int i = 0; i < chunk; ++i) {
    const int idx = base + i;
    if (idx < n) s += cnt[idx];
  }
  part[t] = s;
  __syncthreads();
  // Hillis-Steele inclusive scan over 1024 partials
  for (int ofs = 1; ofs < 1024; ofs <<= 1) {
    const int tmp = (t >= ofs) ? part[t - ofs] : 0;
    __syncthreads();
    part[t] += tmp;
    __syncthreads();
  }
  int run = part[t] - s;  // exclusive prefix of this thread's chunk
  for (int i = 0; i < chunk; ++i) {
    const int idx = base + i;
    if (idx < n) {
      off[idx] = run;
      wptr[idx] = run;
      run += cnt[idx];
    }
  }
  if (t == 1023) off[n] = run;   // == E
}

// ---------------- K4: counting-sort scatter of (col, adj) into CSR order ----------------
__global__ __launch_bounds__(256) void sort_kernel(
    const int* __restrict__ row, const int* __restrict__ col,
    const float* __restrict__ adj, int* __restrict__ wptr,
    int* __restrict__ scol, float* __restrict__ sadj, int E) {
  const int e = blockIdx.x * 256 + threadIdx.x;
  if (e >= E) return;
  const int r = row[e];
  const int pos = atomicAdd(wptr + r, 1);
  scol[pos] = col[e];
  sadj[pos] = adj[e];
}

// ---------------- K5: per-node attention + SpMM (no atomics) ----------------
// 1 block of 128 threads per node.
__global__ __launch_bounds__(128) void node_kernel(
    const float* __restrict__ x, const float* __restrict__ a_row,
    const float* __restrict__ a_col, const int* __restrict__ off,
    const int* __restrict__ scol, const float* __restrict__ sadj,
    float* __restrict__ pbuf, float* __restrict__ feat) {
  const int i = blockIdx.x;
  const int t = threadIdx.x;
  const int off0 = off[i];
  const int off1 = off[i + 1];

  __shared__ float s_ar[DA];
  __shared__ float red[128];
  if (t < DA) s_ar[t] = a_row[(size_t)i * DA + t];
  __syncthreads();

  // Phase 1: p_e = exp(leaky(a_row[i] . a_col[c_e])); partial deg sum.
  float part = 0.f;
  for (int e = off0 + t; e < off1; e += 128) {
    const int c = scol[e];
    const float4* ac = (const float4*)(a_col + (size_t)c * DA);
    const float4* ar4 = (const float4*)s_ar;
    float dot = 0.f;
#pragma unroll
    for (int k = 0; k < DA / 4; ++k) {
      const float4 u = ar4[k];   // LDS broadcast (same addr all lanes)
      const float4 v = ac[k];
      dot += u.x * v.x + u.y * v.y + u.z * v.z + u.w * v.w;
    }
    const float l = (dot >= 0.f) ? dot : SLOPE * dot;
    const float pe = __expf(l);
    pbuf[e] = pe;
    part += pe;
  }
  red[t] = part;
  __syncthreads();
#pragma unroll
  for (int s = 64; s > 0; s >>= 1) {
    if (t < s) red[t] += red[t + s];
    __syncthreads();
  }
  const float deg = red[0];
  const float inv = 0.5f / (deg + 1e-15f);

  // Phase 2: feat[i][t] = sum_e (0.5*adj_e + p_e*inv) * x[c_e][t]
  float acc = 0.f;
  int e = off0;
  for (; e + 1 < off1; e += 2) {
    const int c0 = scol[e];
    const int c1 = scol[e + 1];
    const float v0 = 0.5f * sadj[e] + pbuf[e] * inv;
    const float v1 = 0.5f * sadj[e + 1] + pbuf[e + 1] * inv;
    acc += v0 * x[(size_t)c0 * DIN + t] + v1 * x[(size_t)c1 * DIN + t];
  }
  if (e < off1) {
    const int c0 = scol[e];
    acc += (0.5f * sadj[e] + pbuf[e] * inv) * x[(size_t)c0 * DIN + t];
  }
  feat[(size_t)i * DIN + t] = acc;
}

// ---------------- K6: dense GEMM out = feat @ W_x + b ----------------
__global__ __launch_bounds__(256) void gemm_kernel(
    const float* __restrict__ feat, const float* __restrict__ Wx,
    const float* __restrict__ bx, float* __restrict__ out) {
  __shared__ float fs[16][DIN];   // 8 KB
  const int t = threadIdx.x;
  const int row0 = blockIdx.x * 16;
  {
    const float4* fg = (const float4*)(feat + (size_t)row0 * DIN);
    float4* fs4 = (float4*)fs;
    fs4[t] = fg[t];
    fs4[t + 256] = fg[t + 256];
  }
  __syncthreads();

  float acc[16];
#pragma unroll
  for (int r = 0; r < 16; ++r) acc[r] = 0.f;

  for (int k = 0; k < DIN; k += 4) {
    const float w0 = Wx[(k + 0) * DOUT + t];
    const float w1 = Wx[(k + 1) * DOUT + t];
    const float w2 = Wx[(k + 2) * DOUT + t];
    const float w3 = Wx[(k + 3) * DOUT + t];
#pragma unroll
    for (int r = 0; r < 16; ++r) {
      const float4 f = *(const float4*)&fs[r][k];
      acc[r] += f.x * w0 + f.y * w1 + f.z * w2 + f.w * w3;
    }
  }

  const float b = bx[t];
#pragma unroll
  for (int r = 0; r < 16; ++r)
    out[(size_t)(row0 + r) * DOUT + t] = acc[r] + b;
}

extern "C" void kernel_launch(void* const* d_in, const int* in_sizes, int n_in,
                              void* d_out, int out_size, void* d_ws, size_t ws_size,
                              hipStream_t stream) {
  const float* x   = (const float*)d_in[0];
  const int*   row = (const int*)d_in[1];
  const int*   col = (const int*)d_in[2];
  const float* adj = (const float*)d_in[3];
  const float* Wr  = (const float*)d_in[4];
  const float* Wc  = (const float*)d_in[5];
  const float* Wx  = (const float*)d_in[6];
  const float* bx  = (const float*)d_in[7];
  float* out = (float*)d_out;

  const int n = in_sizes[0] / DIN;   // 50000
  const int E = in_sizes[1];         // 1600000

  // Workspace layout:
  //  floats: a_row[n*32] a_col[n*32] sadj[E] pbuf[E] feat[n*128]
  //  ints:   cnt[n] off[n+1] wptr[n] scol[E]
  float* a_row = (float*)d_ws;
  float* a_col = a_row + (size_t)n * DA;
  float* sadj  = a_col + (size_t)n * DA;
  float* pbuf  = sadj + E;
  float* feat  = pbuf + E;
  int*   cnt   = (int*)(feat + (size_t)n * DIN);
  int*   off   = cnt + n;
  int*   wptr  = off + (n + 1);
  int*   scol  = wptr + n;
  // Total ~= 58 MB

  hipMemsetAsync(cnt, 0, (size_t)n * sizeof(int), stream);

  proj_kernel<<<n / 8, 256, 0, stream>>>(x, Wr, Wc, a_row, a_col);
  hist_kernel<<<(E + 255) / 256, 256, 0, stream>>>(row, cnt, E);
  scan_kernel<<<1, 1024, 0, stream>>>(cnt, off, wptr, n);
  sort_kernel<<<(E + 255) / 256, 256, 0, stream>>>(row, col, adj, wptr, scol, sadj, E);
  node_kernel<<<n, 128, 0, stream>>>(x, a_row, a_col, off, scol, sadj, pbuf, feat);
  gemm_kernel<<<n / 16, 256, 0, stream>>>(feat, Wx, bx, out);
}

// Round 3
// 563.185 us; speedup vs baseline: 1.7450x; 1.2490x over previous
//
#include <hip/hip_runtime.h>

// ComHG graph attention: N=50000, E=1.6M, DIN=128, DOUT=256, DA=32
// Round 3: cheap CSR build + pure-gather SpMM.
//   memset  deg,cnt
//   K1 proj:  a_row = x@W_row * rsqrt(DA), a_col = x@W_col           [N,32]
//   K2 edge:  p[e]=exp(leaky(a_row[r].a_col[c])); deg[r]+=p; cnt[r]++ (fused hist)
//   K3 scan:  3-kernel parallel exclusive scan -> off, wptr
//   K4 sort:  val = 0.5*adj + p * 0.5/(deg[r]+1e-15);  pk[wptr[r]++] = {col, val}
//   K5 node:  wave-per-node: feat[i][:] = sum_e val_e * x[c_e][:]    (no atomics)
//   K6 gemm:  out = feat @ W_x + b_x                                 [N,256]
// (global-max shift dropped: cancels in p/deg up to 1e-15 eps; verified absmax 0.031)

#define DIN   128
#define DOUT  256
#define DA    32
#define SLOPE 0.2f
#define RSQRT_DA 0.17677669529663687f   // 1/sqrt(32)

// ---------------- K1: per-node attention projections ----------------
__global__ __launch_bounds__(256) void proj_kernel(
    const float* __restrict__ x, const float* __restrict__ Wr,
    const float* __restrict__ Wc, float* __restrict__ a_row,
    float* __restrict__ a_col) {
  __shared__ float sWr[DIN][DA];   // 16 KB
  __shared__ float sWc[DIN][DA];   // 16 KB
  __shared__ float sx[8][DIN];     //  4 KB
  const int t = threadIdx.x;
  {
    const float4* wr4 = (const float4*)Wr;
    const float4* wc4 = (const float4*)Wc;
    float4* sr4 = (float4*)sWr;
    float4* sc4 = (float4*)sWc;
#pragma unroll
    for (int i = 0; i < 4; ++i) {
      sr4[t + 256 * i] = wr4[t + 256 * i];
      sc4[t + 256 * i] = wc4[t + 256 * i];
    }
  }
  const int node0 = blockIdx.x * 8;
  {
    const float4* xg = (const float4*)(x + (size_t)node0 * DIN);
    ((float4*)sx)[t] = xg[t];
  }
  __syncthreads();

  const int node = t >> 5;
  const int da = t & 31;
  float ar = 0.f, ac = 0.f;
#pragma unroll
  for (int k = 0; k < DIN; ++k) {
    const float xv = sx[node][k];
    ar += xv * sWr[k][da];
    ac += xv * sWc[k][da];
  }
  const int g = (node0 + node) * DA + da;
  a_row[g] = ar * RSQRT_DA;
  a_col[g] = ac;
}

// ---------------- K2: fused edge logits + degree hist ----------------
__global__ __launch_bounds__(256) void edge_kernel(
    const int* __restrict__ row, const int* __restrict__ col,
    const float* __restrict__ a_row, const float* __restrict__ a_col,
    float* __restrict__ p, float* __restrict__ deg,
    int* __restrict__ cnt, int E) {
  const int e = blockIdx.x * 256 + threadIdx.x;
  if (e >= E) return;
  const int r = row[e];
  const int c = col[e];
  atomicAdd(cnt + r, 1);
  const float4* ar = (const float4*)(a_row + (size_t)r * DA);
  const float4* ac = (const float4*)(a_col + (size_t)c * DA);
  float dot = 0.f;
#pragma unroll
  for (int k = 0; k < DA / 4; ++k) {
    const float4 u = ar[k];
    const float4 v = ac[k];
    dot += u.x * v.x + u.y * v.y + u.z * v.z + u.w * v.w;
  }
  const float l = (dot >= 0.f) ? dot : SLOPE * dot;
  const float pe = __expf(l);
  p[e] = pe;
  atomicAdd(deg + r, pe);
}

// ---------------- K3: parallel exclusive scan (3 kernels) ----------------
__global__ __launch_bounds__(256) void scan1_kernel(
    const int* __restrict__ cnt, int* __restrict__ bsum, int n) {
  __shared__ int red[256];
  const int t = threadIdx.x;
  const int idx = blockIdx.x * 256 + t;
  red[t] = (idx < n) ? cnt[idx] : 0;
  __syncthreads();
#pragma unroll
  for (int s = 128; s > 0; s >>= 1) {
    if (t < s) red[t] += red[t + s];
    __syncthreads();
  }
  if (t == 0) bsum[blockIdx.x] = red[0];
}

__global__ __launch_bounds__(256) void scan2_kernel(
    const int* __restrict__ bsum, int* __restrict__ bpre, int nb) {
  __shared__ int s[256];
  const int t = threadIdx.x;
  const int v = (t < nb) ? bsum[t] : 0;
  s[t] = v;
  __syncthreads();
#pragma unroll
  for (int ofs = 1; ofs < 256; ofs <<= 1) {
    const int tmp = (t >= ofs) ? s[t - ofs] : 0;
    __syncthreads();
    s[t] += tmp;
    __syncthreads();
  }
  if (t < nb) bpre[t] = s[t] - v;
}

__global__ __launch_bounds__(256) void scan3_kernel(
    const int* __restrict__ cnt, const int* __restrict__ bpre,
    int* __restrict__ off, int* __restrict__ wptr, int n) {
  __shared__ int s[256];
  const int t = threadIdx.x;
  const int idx = blockIdx.x * 256 + t;
  const int v = (idx < n) ? cnt[idx] : 0;
  s[t] = v;
  __syncthreads();
#pragma unroll
  for (int ofs = 1; ofs < 256; ofs <<= 1) {
    const int tmp = (t >= ofs) ? s[t - ofs] : 0;
    __syncthreads();
    s[t] += tmp;
    __syncthreads();
  }
  const int excl = bpre[blockIdx.x] + s[t] - v;
  if (idx <= n) off[idx] = excl;     // idx==n lands here -> off[n] = E
  if (idx < n) wptr[idx] = excl;
}

// ---------------- K4: counting-sort scatter of packed {col, val} ----------------
__global__ __launch_bounds__(256) void sort_kernel(
    const int* __restrict__ row, const int* __restrict__ col,
    const float* __restrict__ adj, const float* __restrict__ p,
    const float* __restrict__ deg, int* __restrict__ wptr,
    int2* __restrict__ pk, int E) {
  const int e = blockIdx.x * 256 + threadIdx.x;
  if (e >= E) return;
  const int r = row[e];
  const float val = 0.5f * adj[e] + p[e] * (0.5f / (deg[r] + 1e-15f));
  const int pos = atomicAdd(wptr + r, 1);
  pk[pos] = make_int2(col[e], __float_as_int(val));
}

// ---------------- K5: wave-per-node SpMM (pure gather, no atomics) ----------------
// block = 256 = 4 waves = 4 nodes; lane handles dims 2*lane..2*lane+1 (float2).
__global__ __launch_bounds__(256) void node_kernel(
    const float* __restrict__ x, const int* __restrict__ off,
    const int2* __restrict__ pk, float* __restrict__ feat, int n) {
  __shared__ int2 spk[4][64];   // 2 KB
  const int t = threadIdx.x;
  const int w = t >> 6;
  const int lane = t & 63;
  const int i = blockIdx.x * 4 + w;
  if (i >= n) return;
  const int off0 = off[i];
  const int off1 = off[i + 1];
  const float2* x2 = (const float2*)x;
  float accx = 0.f, accy = 0.f;

  for (int base = off0; base < off1; base += 64) {
    const int m = min(64, off1 - base);
    if (lane < m) spk[w][lane] = pk[base + lane];   // same-wave, no barrier needed
    int j = 0;
    for (; j + 4 <= m; j += 4) {
      const int2 e0 = spk[w][j + 0];
      const int2 e1 = spk[w][j + 1];
      const int2 e2 = spk[w][j + 2];
      const int2 e3 = spk[w][j + 3];
      const float2 x0 = x2[(size_t)e0.x * 64 + lane];
      const float2 x1 = x2[(size_t)e1.x * 64 + lane];
      const float2 xa = x2[(size_t)e2.x * 64 + lane];
      const float2 x3 = x2[(size_t)e3.x * 64 + lane];
      const float v0 = __int_as_float(e0.y);
      const float v1 = __int_as_float(e1.y);
      const float v2 = __int_as_float(e2.y);
      const float v3 = __int_as_float(e3.y);
      accx += v0 * x0.x + v1 * x1.x + v2 * xa.x + v3 * x3.x;
      accy += v0 * x0.y + v1 * x1.y + v2 * xa.y + v3 * x3.y;
    }
    for (; j < m; ++j) {
      const int2 e0 = spk[w][j];
      const float2 x0 = x2[(size_t)e0.x * 64 + lane];
      const float v0 = __int_as_float(e0.y);
      accx += v0 * x0.x;
      accy += v0 * x0.y;
    }
  }
  ((float2*)feat)[(size_t)i * 64 + lane] = make_float2(accx, accy);
}

// ---------------- K6: dense GEMM out = feat @ W_x + b ----------------
__global__ __launch_bounds__(256) void gemm_kernel(
    const float* __restrict__ feat, const float* __restrict__ Wx,
    const float* __restrict__ bx, float* __restrict__ out) {
  __shared__ float fs[16][DIN];   // 8 KB
  const int t = threadIdx.x;
  const int row0 = blockIdx.x * 16;
  {
    const float4* fg = (const float4*)(feat + (size_t)row0 * DIN);
    float4* fs4 = (float4*)fs;
    fs4[t] = fg[t];
    fs4[t + 256] = fg[t + 256];
  }
  __syncthreads();

  float acc[16];
#pragma unroll
  for (int r = 0; r < 16; ++r) acc[r] = 0.f;

  for (int k = 0; k < DIN; k += 4) {
    const float w0 = Wx[(k + 0) * DOUT + t];
    const float w1 = Wx[(k + 1) * DOUT + t];
    const float w2 = Wx[(k + 2) * DOUT + t];
    const float w3 = Wx[(k + 3) * DOUT + t];
#pragma unroll
    for (int r = 0; r < 16; ++r) {
      const float4 f = *(const float4*)&fs[r][k];
      acc[r] += f.x * w0 + f.y * w1 + f.z * w2 + f.w * w3;
    }
  }

  const float b = bx[t];
#pragma unroll
  for (int r = 0; r < 16; ++r)
    out[(size_t)(row0 + r) * DOUT + t] = acc[r] + b;
}

extern "C" void kernel_launch(void* const* d_in, const int* in_sizes, int n_in,
                              void* d_out, int out_size, void* d_ws, size_t ws_size,
                              hipStream_t stream) {
  const float* x   = (const float*)d_in[0];
  const int*   row = (const int*)d_in[1];
  const int*   col = (const int*)d_in[2];
  const float* adj = (const float*)d_in[3];
  const float* Wr  = (const float*)d_in[4];
  const float* Wc  = (const float*)d_in[5];
  const float* Wx  = (const float*)d_in[6];
  const float* bx  = (const float*)d_in[7];
  float* out = (float*)d_out;

  const int n = in_sizes[0] / DIN;   // 50000
  const int E = in_sizes[1];         // 1600000
  const int nb = (n + 255) / 256;    // 196 scan blocks

  // Workspace layout (4-byte units, pk aligned to 8B):
  float* a_row = (float*)d_ws;                    // n*32
  float* a_col = a_row + (size_t)n * DA;          // n*32
  float* p     = a_col + (size_t)n * DA;          // E
  float* deg   = p + E;                           // n   (zeroed)
  int*   cnt   = (int*)(deg + n);                 // n   (zeroed, contiguous w/ deg)
  int*   off   = cnt + n;                         // n+1
  int*   wptr  = off + (n + 1);                   // n
  int*   bsum  = wptr + n;                        // nb
  int*   bpre  = bsum + nb;                       // nb
  size_t used  = (size_t)(bpre + nb - (int*)d_ws);
  used = (used + 1) & ~(size_t)1;                 // 8B-align pk
  int2*  pk    = (int2*)((int*)d_ws + used);      // E int2
  float* feat  = (float*)(pk + E);                // n*128
  // total ~= 58.4 MB

  hipMemsetAsync(deg, 0, (size_t)n * 2 * sizeof(float), stream);  // deg + cnt

  proj_kernel<<<n / 8, 256, 0, stream>>>(x, Wr, Wc, a_row, a_col);
  edge_kernel<<<(E + 255) / 256, 256, 0, stream>>>(row, col, a_row, a_col, p, deg, cnt, E);
  scan1_kernel<<<nb, 256, 0, stream>>>(cnt, bsum, n);
  scan2_kernel<<<1, 256, 0, stream>>>(bsum, bpre, nb);
  scan3_kernel<<<nb, 256, 0, stream>>>(cnt, bpre, off, wptr, n);
  sort_kernel<<<(E + 255) / 256, 256, 0, stream>>>(row, col, adj, p, deg, wptr, pk, E);
  node_kernel<<<(n + 3) / 4, 256, 0, stream>>>(x, off, pk, feat, n);
  gemm_kernel<<<n / 16, 256, 0, stream>>>(feat, Wx, bx, out);
}

// Round 4
// 522.344 us; speedup vs baseline: 1.8815x; 1.0782x over previous
//
#include <hip/hip_runtime.h>

// ComHG graph attention: N=50000, E=1.6M, DIN=128, DOUT=256, DA=32
// Round 4: fold attention-logit compute INTO the node SpMM (no edge kernel,
// no deg atomics, no global p round-trip). Normalization distributes:
//   feat[i] = 0.5*sum_e adj_e*x[c_e] + (0.5/(deg_i+1e-15))*sum_e p_e*x[c_e]
// so a single CSR pass accumulates acc_adj, acc_p, deg and normalizes at end.
// Pipeline:
//   memset cnt
//   K1 proj:  a_row = x@W_row * rsqrt(DA), a_col = x@W_col           [N,32]
//   K2 hist:  cnt[row[e]]++                                           (int atomics)
//   K3 scan:  3-kernel parallel exclusive scan -> off, wptr
//   K4 sort:  pk[wptr[r]++] = {col, adj}
//   K5 node:  wave-per-node fused logits+softmax+SpMM (no atomics)
//   K6 gemm:  out = feat @ W_x + b_x                                  [N,256]
// (global-max shift dropped: cancels in p/deg up to 1e-15 eps; absmax 0.031 ok)

#define DIN   128
#define DOUT  256
#define DA    32
#define SLOPE 0.2f
#define RSQRT_DA 0.17677669529663687f   // 1/sqrt(32)

// ---------------- K1: per-node attention projections ----------------
__global__ __launch_bounds__(256) void proj_kernel(
    const float* __restrict__ x, const float* __restrict__ Wr,
    const float* __restrict__ Wc, float* __restrict__ a_row,
    float* __restrict__ a_col) {
  __shared__ float sWr[DIN][DA];   // 16 KB
  __shared__ float sWc[DIN][DA];   // 16 KB
  __shared__ float sx[8][DIN];     //  4 KB
  const int t = threadIdx.x;
  {
    const float4* wr4 = (const float4*)Wr;
    const float4* wc4 = (const float4*)Wc;
    float4* sr4 = (float4*)sWr;
    float4* sc4 = (float4*)sWc;
#pragma unroll
    for (int i = 0; i < 4; ++i) {
      sr4[t + 256 * i] = wr4[t + 256 * i];
      sc4[t + 256 * i] = wc4[t + 256 * i];
    }
  }
  const int node0 = blockIdx.x * 8;
  {
    const float4* xg = (const float4*)(x + (size_t)node0 * DIN);
    ((float4*)sx)[t] = xg[t];
  }
  __syncthreads();

  const int node = t >> 5;
  const int da = t & 31;
  float ar = 0.f, ac = 0.f;
#pragma unroll
  for (int k = 0; k < DIN; ++k) {
    const float xv = sx[node][k];
    ar += xv * sWr[k][da];
    ac += xv * sWc[k][da];
  }
  const int g = (node0 + node) * DA + da;
  a_row[g] = ar * RSQRT_DA;
  a_col[g] = ac;
}

// ---------------- K2: degree histogram ----------------
__global__ __launch_bounds__(256) void hist_kernel(
    const int* __restrict__ row, int* __restrict__ cnt, int E) {
  const int e = blockIdx.x * 256 + threadIdx.x;
  if (e < E) atomicAdd(cnt + row[e], 1);
}

// ---------------- K3: parallel exclusive scan (3 kernels) ----------------
__global__ __launch_bounds__(256) void scan1_kernel(
    const int* __restrict__ cnt, int* __restrict__ bsum, int n) {
  __shared__ int red[256];
  const int t = threadIdx.x;
  const int idx = blockIdx.x * 256 + t;
  red[t] = (idx < n) ? cnt[idx] : 0;
  __syncthreads();
#pragma unroll
  for (int s = 128; s > 0; s >>= 1) {
    if (t < s) red[t] += red[t + s];
    __syncthreads();
  }
  if (t == 0) bsum[blockIdx.x] = red[0];
}

__global__ __launch_bounds__(256) void scan2_kernel(
    const int* __restrict__ bsum, int* __restrict__ bpre, int nb) {
  __shared__ int s[256];
  const int t = threadIdx.x;
  const int v = (t < nb) ? bsum[t] : 0;
  s[t] = v;
  __syncthreads();
#pragma unroll
  for (int ofs = 1; ofs < 256; ofs <<= 1) {
    const int tmp = (t >= ofs) ? s[t - ofs] : 0;
    __syncthreads();
    s[t] += tmp;
    __syncthreads();
  }
  if (t < nb) bpre[t] = s[t] - v;
}

__global__ __launch_bounds__(256) void scan3_kernel(
    const int* __restrict__ cnt, const int* __restrict__ bpre,
    int* __restrict__ off, int* __restrict__ wptr, int n) {
  __shared__ int s[256];
  const int t = threadIdx.x;
  const int idx = blockIdx.x * 256 + t;
  const int v = (idx < n) ? cnt[idx] : 0;
  s[t] = v;
  __syncthreads();
#pragma unroll
  for (int ofs = 1; ofs < 256; ofs <<= 1) {
    const int tmp = (t >= ofs) ? s[t - ofs] : 0;
    __syncthreads();
    s[t] += tmp;
    __syncthreads();
  }
  const int excl = bpre[blockIdx.x] + s[t] - v;
  if (idx <= n) off[idx] = excl;     // idx==n lands here -> off[n] = E
  if (idx < n) wptr[idx] = excl;
}

// ---------------- K4: counting-sort scatter of packed {col, adj} ----------------
__global__ __launch_bounds__(256) void sort_kernel(
    const int* __restrict__ row, const int* __restrict__ col,
    const float* __restrict__ adj, int* __restrict__ wptr,
    int2* __restrict__ pk, int E) {
  const int e = blockIdx.x * 256 + threadIdx.x;
  if (e >= E) return;
  const int r = row[e];
  const int pos = atomicAdd(wptr + r, 1);
  pk[pos] = make_int2(col[e], __float_as_int(adj[e]));
}

// ---------------- K5: wave-per-node fused logits+softmax+SpMM ----------------
// block = 256 = 4 waves = 4 nodes; lane handles dims 2*lane..2*lane+1 (float2).
// Per 64-edge chunk: lane j computes p_j = exp(leaky(a_row[i].a_col[c_j]))
// into LDS (same-wave RAW, no barrier), then all lanes accumulate
// acc_adj += adj_j*x, acc_p += p_j*x, deg += p_j. Normalize once at the end.
__global__ __launch_bounds__(256) void node_kernel(
    const float* __restrict__ x, const float* __restrict__ a_row,
    const float* __restrict__ a_col, const int* __restrict__ off,
    const int2* __restrict__ pk, float* __restrict__ feat, int n) {
  __shared__ int2  spk[4][64];   // 2 KB {col, adj}
  __shared__ float sp[4][64];    // 1 KB p
  __shared__ float s_ar[4][DA];  // 0.5 KB a_row[i]
  const int t = threadIdx.x;
  const int w = t >> 6;
  const int lane = t & 63;
  const int i = blockIdx.x * 4 + w;
  if (i >= n) return;
  if (lane < DA) s_ar[w][lane] = a_row[(size_t)i * DA + lane];
  const int off0 = off[i];
  const int off1 = off[i + 1];
  const float2* x2 = (const float2*)x;
  float aax = 0.f, aay = 0.f;   // adj-weighted accumulator
  float apx = 0.f, apy = 0.f;   // p-weighted accumulator
  float deg = 0.f;

  for (int base = off0; base < off1; base += 64) {
    const int m = min(64, off1 - base);
    if (lane < m) {
      const int2 e = pk[base + lane];
      spk[w][lane] = e;
      const float4* ac = (const float4*)(a_col + (size_t)e.x * DA);
      const float4* ar = (const float4*)s_ar[w];   // broadcast reads
      float dot = 0.f;
#pragma unroll
      for (int k = 0; k < DA / 4; ++k) {
        const float4 u = ar[k];
        const float4 v = ac[k];
        dot += u.x * v.x + u.y * v.y + u.z * v.z + u.w * v.w;
      }
      const float l = (dot >= 0.f) ? dot : SLOPE * dot;
      sp[w][lane] = __expf(l);
    }
    int j = 0;
    for (; j + 4 <= m; j += 4) {
      const int2 e0 = spk[w][j + 0];
      const int2 e1 = spk[w][j + 1];
      const int2 e2 = spk[w][j + 2];
      const int2 e3 = spk[w][j + 3];
      const float p0 = sp[w][j + 0];
      const float p1 = sp[w][j + 1];
      const float p2 = sp[w][j + 2];
      const float p3 = sp[w][j + 3];
      const float2 x0 = x2[(size_t)e0.x * 64 + lane];
      const float2 x1 = x2[(size_t)e1.x * 64 + lane];
      const float2 xa = x2[(size_t)e2.x * 64 + lane];
      const float2 x3 = x2[(size_t)e3.x * 64 + lane];
      const float a0 = __int_as_float(e0.y);
      const float a1 = __int_as_float(e1.y);
      const float a2 = __int_as_float(e2.y);
      const float a3 = __int_as_float(e3.y);
      aax += a0 * x0.x + a1 * x1.x + a2 * xa.x + a3 * x3.x;
      aay += a0 * x0.y + a1 * x1.y + a2 * xa.y + a3 * x3.y;
      apx += p0 * x0.x + p1 * x1.x + p2 * xa.x + p3 * x3.x;
      apy += p0 * x0.y + p1 * x1.y + p2 * xa.y + p3 * x3.y;
      deg += (p0 + p1) + (p2 + p3);
    }
    for (; j < m; ++j) {
      const int2 e0 = spk[w][j];
      const float p0 = sp[w][j];
      const float2 x0 = x2[(size_t)e0.x * 64 + lane];
      const float a0 = __int_as_float(e0.y);
      aax += a0 * x0.x;
      aay += a0 * x0.y;
      apx += p0 * x0.x;
      apy += p0 * x0.y;
      deg += p0;
    }
  }
  const float inv = 0.5f / (deg + 1e-15f);
  ((float2*)feat)[(size_t)i * 64 + lane] =
      make_float2(0.5f * aax + inv * apx, 0.5f * aay + inv * apy);
}

// ---------------- K6: dense GEMM out = feat @ W_x + b ----------------
__global__ __launch_bounds__(256) void gemm_kernel(
    const float* __restrict__ feat, const float* __restrict__ Wx,
    const float* __restrict__ bx, float* __restrict__ out) {
  __shared__ float fs[16][DIN];   // 8 KB
  const int t = threadIdx.x;
  const int row0 = blockIdx.x * 16;
  {
    const float4* fg = (const float4*)(feat + (size_t)row0 * DIN);
    float4* fs4 = (float4*)fs;
    fs4[t] = fg[t];
    fs4[t + 256] = fg[t + 256];
  }
  __syncthreads();

  float acc[16];
#pragma unroll
  for (int r = 0; r < 16; ++r) acc[r] = 0.f;

  for (int k = 0; k < DIN; k += 4) {
    const float w0 = Wx[(k + 0) * DOUT + t];
    const float w1 = Wx[(k + 1) * DOUT + t];
    const float w2 = Wx[(k + 2) * DOUT + t];
    const float w3 = Wx[(k + 3) * DOUT + t];
#pragma unroll
    for (int r = 0; r < 16; ++r) {
      const float4 f = *(const float4*)&fs[r][k];
      acc[r] += f.x * w0 + f.y * w1 + f.z * w2 + f.w * w3;
    }
  }

  const float b = bx[t];
#pragma unroll
  for (int r = 0; r < 16; ++r)
    out[(size_t)(row0 + r) * DOUT + t] = acc[r] + b;
}

extern "C" void kernel_launch(void* const* d_in, const int* in_sizes, int n_in,
                              void* d_out, int out_size, void* d_ws, size_t ws_size,
                              hipStream_t stream) {
  const float* x   = (const float*)d_in[0];
  const int*   row = (const int*)d_in[1];
  const int*   col = (const int*)d_in[2];
  const float* adj = (const float*)d_in[3];
  const float* Wr  = (const float*)d_in[4];
  const float* Wc  = (const float*)d_in[5];
  const float* Wx  = (const float*)d_in[6];
  const float* bx  = (const float*)d_in[7];
  float* out = (float*)d_out;

  const int n = in_sizes[0] / DIN;   // 50000
  const int E = in_sizes[1];         // 1600000
  const int nb = (n + 255) / 256;    // 196 scan blocks

  // Workspace layout (4-byte units, pk aligned to 8B):
  float* a_row = (float*)d_ws;                    // n*32
  float* a_col = a_row + (size_t)n * DA;          // n*32
  int*   cnt   = (int*)(a_col + (size_t)n * DA);  // n   (zeroed)
  int*   off   = cnt + n;                         // n+1
  int*   wptr  = off + (n + 1);                   // n
  int*   bsum  = wptr + n;                        // nb
  int*   bpre  = bsum + nb;                       // nb
  size_t used  = (size_t)(bpre + nb - (int*)d_ws);
  used = (used + 1) & ~(size_t)1;                 // 8B-align pk
  int2*  pk    = (int2*)((int*)d_ws + used);      // E int2
  float* feat  = (float*)(pk + E);                // n*128
  // total ~= 52 MB

  hipMemsetAsync(cnt, 0, (size_t)n * sizeof(int), stream);

  proj_kernel<<<n / 8, 256, 0, stream>>>(x, Wr, Wc, a_row, a_col);
  hist_kernel<<<(E + 255) / 256, 256, 0, stream>>>(row, cnt, E);
  scan1_kernel<<<nb, 256, 0, stream>>>(cnt, bsum, n);
  scan2_kernel<<<1, 256, 0, stream>>>(bsum, bpre, nb);
  scan3_kernel<<<nb, 256, 0, stream>>>(cnt, bpre, off, wptr, n);
  sort_kernel<<<(E + 255) / 256, 256, 0, stream>>>(row, col, adj, wptr, pk, E);
  node_kernel<<<(n + 3) / 4, 256, 0, stream>>>(x, a_row, a_col, off, pk, feat, n);
  gemm_kernel<<<n / 16, 256, 0, stream>>>(feat, Wx, bx, out);
}

// Round 5
// 481.357 us; speedup vs baseline: 2.0417x; 1.0851x over previous
//
#include <hip/hip_runtime.h>

// ComHG graph attention: N=50000, E=1.6M, DIN=128, DOUT=256, DA=32
// Round 5: attack CSR-build atomic line-contention (8-way replicated
// counters, XCD-aligned by blockIdx&7) + bf16 gather operands in node SpMM.
//   memset cnt_rep[8][n]
//   K1 proj:  a_row = x@W_row*rsqrt(DA) (f32); a_colh = bf16(x@W_col);
//             xh = bf16(x)                       (fused, x already in LDS)
//   K2 hist:  cnt_rep[blockIdx&7][row[e]]++
//   K3 scan:  off = prefix(sum_k cnt_rep), wptr_rep[k] = off + partial sums
//   K4 sort:  pos = wptr_rep[blockIdx&7][r]++;  pk[pos] = {col, adj}
//             (same edge->block->k mapping as hist => deterministic ranges)
//   K5 node:  wave-per-node fused logits+softmax+SpMM, bf16 gathers
//   K6 gemm:  out = feat @ W_x + b_x
// (global-max shift dropped: cancels in p/deg up to 1e-15 eps; absmax ok)

#define DIN   128
#define DOUT  256
#define DA    32
#define SLOPE 0.2f
#define RSQRT_DA 0.17677669529663687f   // 1/sqrt(32)
#define NREP  8

typedef unsigned int uint;
typedef unsigned short ushort;

static __device__ __forceinline__ ushort f2bf(float f) {
  // round-to-nearest-even bf16 (inputs are finite/normal)
  const uint u = __float_as_uint(f);
  return (ushort)((u + 0x7fffu + ((u >> 16) & 1u)) >> 16);
}

// ---------------- K1: projections + bf16 copies ----------------
__global__ __launch_bounds__(256) void proj_kernel(
    const float* __restrict__ x, const float* __restrict__ Wr,
    const float* __restrict__ Wc, float* __restrict__ a_row,
    ushort* __restrict__ a_colh, ushort* __restrict__ xh) {
  __shared__ float sWr[DIN][DA];   // 16 KB
  __shared__ float sWc[DIN][DA];   // 16 KB
  __shared__ float sx[8][DIN];     //  4 KB
  const int t = threadIdx.x;
  {
    const float4* wr4 = (const float4*)Wr;
    const float4* wc4 = (const float4*)Wc;
    float4* sr4 = (float4*)sWr;
    float4* sc4 = (float4*)sWc;
#pragma unroll
    for (int i = 0; i < 4; ++i) {
      sr4[t + 256 * i] = wr4[t + 256 * i];
      sc4[t + 256 * i] = wc4[t + 256 * i];
    }
  }
  const int node0 = blockIdx.x * 8;
  {
    const float4* xg = (const float4*)(x + (size_t)node0 * DIN);
    const float4 v = xg[t];
    ((float4*)sx)[t] = v;
    // bf16 copy of x (own element, no sync needed)
    ushort4 h;
    h.x = f2bf(v.x); h.y = f2bf(v.y); h.z = f2bf(v.z); h.w = f2bf(v.w);
    ((ushort4*)(xh + (size_t)node0 * DIN))[t] = h;
  }
  __syncthreads();

  const int node = t >> 5;
  const int da = t & 31;
  float ar = 0.f, ac = 0.f;
#pragma unroll
  for (int k = 0; k < DIN; ++k) {
    const float xv = sx[node][k];
    ar += xv * sWr[k][da];
    ac += xv * sWc[k][da];
  }
  const int g = (node0 + node) * DA + da;
  a_row[g] = ar * RSQRT_DA;
  a_colh[g] = f2bf(ac);
}

// ---------------- K2: replicated degree histogram ----------------
__global__ __launch_bounds__(256) void hist_kernel(
    const int* __restrict__ row, int* __restrict__ cnt_rep, int n, int E) {
  const int e = blockIdx.x * 256 + threadIdx.x;
  const int k = blockIdx.x & (NREP - 1);
  if (e < E) atomicAdd(cnt_rep + (size_t)k * n + row[e], 1);
}

// ---------------- K3: parallel exclusive scan (3 kernels) ----------------
__global__ __launch_bounds__(256) void scan1_kernel(
    const int* __restrict__ cnt_rep, int* __restrict__ bsum, int n) {
  __shared__ int red[256];
  const int t = threadIdx.x;
  const int idx = blockIdx.x * 256 + t;
  int v = 0;
  if (idx < n) {
#pragma unroll
    for (int k = 0; k < NREP; ++k) v += cnt_rep[(size_t)k * n + idx];
  }
  red[t] = v;
  __syncthreads();
#pragma unroll
  for (int s = 128; s > 0; s >>= 1) {
    if (t < s) red[t] += red[t + s];
    __syncthreads();
  }
  if (t == 0) bsum[blockIdx.x] = red[0];
}

__global__ __launch_bounds__(256) void scan2_kernel(
    const int* __restrict__ bsum, int* __restrict__ bpre, int nb) {
  __shared__ int s[256];
  const int t = threadIdx.x;
  const int v = (t < nb) ? bsum[t] : 0;
  s[t] = v;
  __syncthreads();
#pragma unroll
  for (int ofs = 1; ofs < 256; ofs <<= 1) {
    const int tmp = (t >= ofs) ? s[t - ofs] : 0;
    __syncthreads();
    s[t] += tmp;
    __syncthreads();
  }
  if (t < nb) bpre[t] = s[t] - v;
}

__global__ __launch_bounds__(256) void scan3_kernel(
    const int* __restrict__ cnt_rep, const int* __restrict__ bpre,
    int* __restrict__ off, int* __restrict__ wptr_rep, int n) {
  __shared__ int s[256];
  const int t = threadIdx.x;
  const int idx = blockIdx.x * 256 + t;
  int c[NREP];
  int v = 0;
  if (idx < n) {
#pragma unroll
    for (int k = 0; k < NREP; ++k) {
      c[k] = cnt_rep[(size_t)k * n + idx];
      v += c[k];
    }
  }
  s[t] = v;
  __syncthreads();
#pragma unroll
  for (int ofs = 1; ofs < 256; ofs <<= 1) {
    const int tmp = (t >= ofs) ? s[t - ofs] : 0;
    __syncthreads();
    s[t] += tmp;
    __syncthreads();
  }
  const int excl = bpre[blockIdx.x] + s[t] - v;
  if (idx <= n) off[idx] = excl;     // idx==n -> off[n] = E
  if (idx < n) {
    int base = excl;
#pragma unroll
    for (int k = 0; k < NREP; ++k) {   // coalesced per k
      wptr_rep[(size_t)k * n + idx] = base;
      base += c[k];
    }
  }
}

// ---------------- K4: counting-sort scatter (replicated wptr) ----------------
__global__ __launch_bounds__(256) void sort_kernel(
    const int* __restrict__ row, const int* __restrict__ col,
    const float* __restrict__ adj, int* __restrict__ wptr_rep,
    int2* __restrict__ pk, int n, int E) {
  const int e = blockIdx.x * 256 + threadIdx.x;
  if (e >= E) return;
  const int k = blockIdx.x & (NREP - 1);   // must match hist mapping
  const int r = row[e];
  const int pos = atomicAdd(wptr_rep + (size_t)k * n + r, 1);
  pk[pos] = make_int2(col[e], __float_as_int(adj[e]));
}

// ---------------- K5: wave-per-node fused logits+softmax+SpMM ----------------
// block = 256 = 4 waves = 4 nodes; lane handles dims 2*lane..2*lane+1 (bf16x2).
__global__ __launch_bounds__(256) void node_kernel(
    const uint* __restrict__ xh, const float* __restrict__ a_row,
    const ushort* __restrict__ a_colh, const int* __restrict__ off,
    const int2* __restrict__ pk, float* __restrict__ feat, int n) {
  __shared__ int2  spk[4][64];   // {col, adj}
  __shared__ float sp[4][64];    // p
  __shared__ float s_ar[4][DA];  // a_row[i]
  const int t = threadIdx.x;
  const int w = t >> 6;
  const int lane = t & 63;
  const int i = blockIdx.x * 4 + w;
  if (i >= n) return;
  if (lane < DA) s_ar[w][lane] = a_row[(size_t)i * DA + lane];
  const int off0 = off[i];
  const int off1 = off[i + 1];
  float aax = 0.f, aay = 0.f;   // adj-weighted accumulator
  float apx = 0.f, apy = 0.f;   // p-weighted accumulator
  float deg = 0.f;

  for (int base = off0; base < off1; base += 64) {
    const int m = min(64, off1 - base);
    if (lane < m) {
      const int2 e = pk[base + lane];
      spk[w][lane] = e;
      const uint4* ac = (const uint4*)(a_colh + (size_t)e.x * DA);
      const float* ar = s_ar[w];
      float dot = 0.f;
#pragma unroll
      for (int k = 0; k < 4; ++k) {
        const uint4 q = ac[k];
        const float* a = ar + k * 8;
        dot += __uint_as_float(q.x << 16) * a[0] +
               __uint_as_float(q.x & 0xffff0000u) * a[1] +
               __uint_as_float(q.y << 16) * a[2] +
               __uint_as_float(q.y & 0xffff0000u) * a[3] +
               __uint_as_float(q.z << 16) * a[4] +
               __uint_as_float(q.z & 0xffff0000u) * a[5] +
               __uint_as_float(q.w << 16) * a[6] +
               __uint_as_float(q.w & 0xffff0000u) * a[7];
      }
      const float l = (dot >= 0.f) ? dot : SLOPE * dot;
      sp[w][lane] = __expf(l);   // same-wave RAW, no barrier needed
    }
    int j = 0;
    for (; j + 8 <= m; j += 8) {
#pragma unroll
      for (int u = 0; u < 8; ++u) {
        const int2 e = spk[w][j + u];
        const float pv = sp[w][j + u];
        const uint xv = xh[(size_t)e.x * 64 + lane];
        const float fx = __uint_as_float(xv << 16);
        const float fy = __uint_as_float(xv & 0xffff0000u);
        const float av = __int_as_float(e.y);
        aax += av * fx; aay += av * fy;
        apx += pv * fx; apy += pv * fy;
        deg += pv;
      }
    }
    for (; j < m; ++j) {
      const int2 e = spk[w][j];
      const float pv = sp[w][j];
      const uint xv = xh[(size_t)e.x * 64 + lane];
      const float fx = __uint_as_float(xv << 16);
      const float fy = __uint_as_float(xv & 0xffff0000u);
      const float av = __int_as_float(e.y);
      aax += av * fx; aay += av * fy;
      apx += pv * fx; apy += pv * fy;
      deg += pv;
    }
  }
  const float inv = 0.5f / (deg + 1e-15f);
  ((float2*)feat)[(size_t)i * 64 + lane] =
      make_float2(0.5f * aax + inv * apx, 0.5f * aay + inv * apy);
}

// ---------------- K6: dense GEMM out = feat @ W_x + b ----------------
__global__ __launch_bounds__(256) void gemm_kernel(
    const float* __restrict__ feat, const float* __restrict__ Wx,
    const float* __restrict__ bx, float* __restrict__ out) {
  __shared__ float fs[16][DIN];   // 8 KB
  const int t = threadIdx.x;
  const int row0 = blockIdx.x * 16;
  {
    const float4* fg = (const float4*)(feat + (size_t)row0 * DIN);
    float4* fs4 = (float4*)fs;
    fs4[t] = fg[t];
    fs4[t + 256] = fg[t + 256];
  }
  __syncthreads();

  float acc[16];
#pragma unroll
  for (int r = 0; r < 16; ++r) acc[r] = 0.f;

  for (int k = 0; k < DIN; k += 4) {
    const float w0 = Wx[(k + 0) * DOUT + t];
    const float w1 = Wx[(k + 1) * DOUT + t];
    const float w2 = Wx[(k + 2) * DOUT + t];
    const float w3 = Wx[(k + 3) * DOUT + t];
#pragma unroll
    for (int r = 0; r < 16; ++r) {
      const float4 f = *(const float4*)&fs[r][k];
      acc[r] += f.x * w0 + f.y * w1 + f.z * w2 + f.w * w3;
    }
  }

  const float b = bx[t];
#pragma unroll
  for (int r = 0; r < 16; ++r)
    out[(size_t)(row0 + r) * DOUT + t] = acc[r] + b;
}

extern "C" void kernel_launch(void* const* d_in, const int* in_sizes, int n_in,
                              void* d_out, int out_size, void* d_ws, size_t ws_size,
                              hipStream_t stream) {
  const float* x   = (const float*)d_in[0];
  const int*   row = (const int*)d_in[1];
  const int*   col = (const int*)d_in[2];
  const float* adj = (const float*)d_in[3];
  const float* Wr  = (const float*)d_in[4];
  const float* Wc  = (const float*)d_in[5];
  const float* Wx  = (const float*)d_in[6];
  const float* bx  = (const float*)d_in[7];
  float* out = (float*)d_out;

  const int n = in_sizes[0] / DIN;   // 50000
  const int E = in_sizes[1];         // 1600000
  const int nb = (n + 255) / 256;    // 196 scan blocks

  // Workspace layout (4-byte cursor; bf16/pk regions 16B-aligned at the end)
  int* w4 = (int*)d_ws;
  float* a_row    = (float*)w4;  w4 += (size_t)n * DA;        // 6.4 MB
  float* feat     = (float*)w4;  w4 += (size_t)n * DIN;       // 25.6 MB
  int*   cnt_rep  = w4;          w4 += (size_t)NREP * n;      // 1.6 MB (zeroed)
  int*   off      = w4;          w4 += n + 1;
  int*   wptr_rep = w4;          w4 += (size_t)NREP * n;      // 1.6 MB
  int*   bsum     = w4;          w4 += nb;
  int*   bpre     = w4;          w4 += nb;
  w4 = (int*)(((uintptr_t)w4 + 15) & ~(uintptr_t)15);
  ushort* a_colh  = (ushort*)w4; w4 += (size_t)n * DA / 2;    // 3.2 MB
  uint*   xh      = (uint*)w4;   w4 += (size_t)n * DIN / 2;   // 12.8 MB
  int2*   pk      = (int2*)w4;                                // 12.8 MB
  // total ~= 64.3 MB

  hipMemsetAsync(cnt_rep, 0, (size_t)NREP * n * sizeof(int), stream);

  proj_kernel<<<n / 8, 256, 0, stream>>>(x, Wr, Wc, a_row, a_colh, (ushort*)xh);
  hist_kernel<<<(E + 255) / 256, 256, 0, stream>>>(row, cnt_rep, n, E);
  scan1_kernel<<<nb, 256, 0, stream>>>(cnt_rep, bsum, n);
  scan2_kernel<<<1, 256, 0, stream>>>(bsum, bpre, nb);
  scan3_kernel<<<nb, 256, 0, stream>>>(cnt_rep, bpre, off, wptr_rep, n);
  sort_kernel<<<(E + 255) / 256, 256, 0, stream>>>(row, col, adj, wptr_rep, pk, n, E);
  node_kernel<<<(n + 3) / 4, 256, 0, stream>>>(xh, a_row, a_colh, off, pk, feat, n);
  gemm_kernel<<<n / 16, 256, 0, stream>>>(feat, Wx, bx, out);
}

// Round 6
// 380.812 us; speedup vs baseline: 2.5808x; 1.2640x over previous
//
#include <hip/hip_runtime.h>

// ComHG graph attention: N=50000, E=1.6M, DIN=128, DOUT=256, DA=32
// Round 6: replace contended counting-sort with a two-level partition sort
// (coarse 128-node buckets, per-(block,bucket) contiguous sub-ranges, then
// bucket-local CSR build with LDS counters). Kills the 94 MB of scattered
// 8B-write line evictions seen in R5's sort_kernel.
// Pipeline:
//   memset bcnt[nb]
//   K1 proj:   a_row(f32) = x@W_row*rsqrt(DA); a_colh = bf16(x@W_col); xh = bf16(x)
//   K2 bhist:  LDS-hist coarse buckets (row>>7), flush to bcnt
//   K3 bscan:  bstart = excl prefix(bcnt); bcursor = bstart       (1 block)
//   K4 part:   per 2048-edge block: LDS hist -> reserve sub-ranges in bcursor
//              -> write ibuf{rowlocal<<16|col, adj} in contiguous runs
//   K5 csr:    per bucket: LDS count[128]+scan -> off[] and pk{col,adj} (local window)
//   K6 node:   wave-per-node fused logits+softmax+SpMM, bf16 gathers (no atomics)
//   K7 gemm:   out = feat @ W_x + b_x
// (global-max shift dropped: cancels in p/deg up to 1e-15 eps; absmax 0.0625 ok)

#define DIN   128
#define DOUT  256
#define DA    32
#define SLOPE 0.2f
#define RSQRT_DA 0.17677669529663687f   // 1/sqrt(32)
#define BSH   7                         // 128 nodes per coarse bucket
#define NBMAX 512                       // LDS sizing; nb = ceil(n/128) = 391
#define BH_CHUNK 4096
#define PB_CHUNK 2048

typedef unsigned int uint;
typedef unsigned short ushort;

static __device__ __forceinline__ ushort f2bf(float f) {
  const uint u = __float_as_uint(f);
  return (ushort)((u + 0x7fffu + ((u >> 16) & 1u)) >> 16);
}

// ---------------- K1: projections + bf16 copies ----------------
__global__ __launch_bounds__(256) void proj_kernel(
    const float* __restrict__ x, const float* __restrict__ Wr,
    const float* __restrict__ Wc, float* __restrict__ a_row,
    ushort* __restrict__ a_colh, ushort* __restrict__ xh) {
  __shared__ float sWr[DIN][DA];
  __shared__ float sWc[DIN][DA];
  __shared__ float sx[8][DIN];
  const int t = threadIdx.x;
  {
    const float4* wr4 = (const float4*)Wr;
    const float4* wc4 = (const float4*)Wc;
    float4* sr4 = (float4*)sWr;
    float4* sc4 = (float4*)sWc;
#pragma unroll
    for (int i = 0; i < 4; ++i) {
      sr4[t + 256 * i] = wr4[t + 256 * i];
      sc4[t + 256 * i] = wc4[t + 256 * i];
    }
  }
  const int node0 = blockIdx.x * 8;
  {
    const float4* xg = (const float4*)(x + (size_t)node0 * DIN);
    const float4 v = xg[t];
    ((float4*)sx)[t] = v;
    ushort4 h;
    h.x = f2bf(v.x); h.y = f2bf(v.y); h.z = f2bf(v.z); h.w = f2bf(v.w);
    ((ushort4*)(xh + (size_t)node0 * DIN))[t] = h;
  }
  __syncthreads();

  const int node = t >> 5;
  const int da = t & 31;
  float ar = 0.f, ac = 0.f;
#pragma unroll
  for (int k = 0; k < DIN; ++k) {
    const float xv = sx[node][k];
    ar += xv * sWr[k][da];
    ac += xv * sWc[k][da];
  }
  const int g = (node0 + node) * DA + da;
  a_row[g] = ar * RSQRT_DA;
  a_colh[g] = f2bf(ac);
}

// ---------------- K2: coarse bucket histogram (LDS-staged) ----------------
__global__ __launch_bounds__(256) void bhist_kernel(
    const int* __restrict__ row, int* __restrict__ bcnt, int nb, int E) {
  __shared__ int hist[NBMAX];
  const int t = threadIdx.x;
  for (int b = t; b < nb; b += 256) hist[b] = 0;
  __syncthreads();
  const int e0 = blockIdx.x * BH_CHUNK;
#pragma unroll
  for (int u = 0; u < BH_CHUNK / 256; ++u) {
    const int e = e0 + u * 256 + t;
    if (e < E) atomicAdd(&hist[row[e] >> BSH], 1);
  }
  __syncthreads();
  for (int b = t; b < nb; b += 256) {
    const int c = hist[b];
    if (c) atomicAdd(&bcnt[b], c);
  }
}

// ---------------- K3: single-block scan over nb buckets ----------------
__global__ __launch_bounds__(512) void bscan_kernel(
    const int* __restrict__ bcnt, int* __restrict__ bstart,
    int* __restrict__ bcursor, int nb) {
  __shared__ int s[512];
  const int t = threadIdx.x;
  const int v = (t < nb) ? bcnt[t] : 0;
  s[t] = v;
  __syncthreads();
  for (int ofs = 1; ofs < 512; ofs <<= 1) {
    const int tmp = (t >= ofs) ? s[t - ofs] : 0;
    __syncthreads();
    s[t] += tmp;
    __syncthreads();
  }
  if (t < nb) {
    const int ex = s[t] - v;
    bstart[t] = ex;
    bcursor[t] = ex;
  }
  if (t == nb) bstart[nb] = s[nb - 1];   // == E
}

// ---------------- K4: partition into coarse buckets ----------------
// Per-(block,bucket) contiguous sub-range => write runs stay line-local.
__global__ __launch_bounds__(256) void part_kernel(
    const int* __restrict__ row, const int* __restrict__ col,
    const float* __restrict__ adj, int* __restrict__ bcursor,
    int2* __restrict__ ibuf, int nb, int E) {
  __shared__ int hist[NBMAX];
  __shared__ int base[NBMAX];
  const int t = threadIdx.x;
  const int e0 = blockIdx.x * PB_CHUNK;
  for (int b = t; b < nb; b += 256) hist[b] = 0;
  __syncthreads();
  int myrow[PB_CHUNK / 256];
#pragma unroll
  for (int u = 0; u < PB_CHUNK / 256; ++u) {
    const int e = e0 + u * 256 + t;
    myrow[u] = (e < E) ? row[e] : -1;
    if (myrow[u] >= 0) atomicAdd(&hist[myrow[u] >> BSH], 1);
  }
  __syncthreads();
  for (int b = t; b < nb; b += 256) {
    const int c = hist[b];
    base[b] = c ? atomicAdd(&bcursor[b], c) : 0;
    hist[b] = 0;   // reuse as intra-block rank counter (same-thread, safe)
  }
  __syncthreads();
#pragma unroll
  for (int u = 0; u < PB_CHUNK / 256; ++u) {
    const int e = e0 + u * 256 + t;
    if (e < E) {
      const int r = myrow[u];
      const int b = r >> BSH;
      const int pos = base[b] + atomicAdd(&hist[b], 1);
      ibuf[pos] = make_int2(((r & 127) << 16) | col[e], __float_as_int(adj[e]));
    }
  }
}

// ---------------- K5: bucket-local CSR build (off + pk) ----------------
__global__ __launch_bounds__(256) void csr_kernel(
    const int* __restrict__ bstart, const int2* __restrict__ ibuf,
    int* __restrict__ off, int2* __restrict__ pk, int n, int E) {
  __shared__ int cnt[128];
  __shared__ int excl[128];
  const int b = blockIdx.x;
  const int t = threadIdx.x;
  const int estart = bstart[b];
  const int eend = bstart[b + 1];
  if (t < 128) cnt[t] = 0;
  __syncthreads();
  for (int e = estart + t; e < eend; e += 256)
    atomicAdd(&cnt[ibuf[e].x >> 16], 1);
  __syncthreads();
  if (t < 128) excl[t] = cnt[t];
  __syncthreads();
  for (int ofs = 1; ofs < 128; ofs <<= 1) {   // inclusive scan
    const int v = (t < 128 && t >= ofs) ? excl[t - ofs] : 0;
    __syncthreads();
    if (t < 128) excl[t] += v;
    __syncthreads();
  }
  if (t < 128) excl[t] -= cnt[t];             // -> exclusive
  __syncthreads();
  const int node0 = b << BSH;
  if (t < 128 && node0 + t < n) off[node0 + t] = estart + excl[t];
  if (b == gridDim.x - 1 && t == 0) off[n] = E;
  if (t < 128) cnt[t] = 0;                    // reuse as rank counter
  __syncthreads();
  for (int e = estart + t; e < eend; e += 256) {
    const int2 v = ibuf[e];
    const int rl = v.x >> 16;
    const int pos = estart + excl[rl] + atomicAdd(&cnt[rl], 1);
    pk[pos] = make_int2(v.x & 0xffff, v.y);   // {col, adj} — 32 KB hot window
  }
}

// ---------------- K6: wave-per-node fused logits+softmax+SpMM ----------------
__global__ __launch_bounds__(256) void node_kernel(
    const uint* __restrict__ xh, const float* __restrict__ a_row,
    const ushort* __restrict__ a_colh, const int* __restrict__ off,
    const int2* __restrict__ pk, float* __restrict__ feat, int n) {
  __shared__ int2  spk[4][64];
  __shared__ float sp[4][64];
  __shared__ float s_ar[4][DA];
  const int t = threadIdx.x;
  const int w = t >> 6;
  const int lane = t & 63;
  const int i = blockIdx.x * 4 + w;
  if (i >= n) return;
  if (lane < DA) s_ar[w][lane] = a_row[(size_t)i * DA + lane];
  const int off0 = off[i];
  const int off1 = off[i + 1];
  float aax = 0.f, aay = 0.f;
  float apx = 0.f, apy = 0.f;
  float deg = 0.f;

  for (int base = off0; base < off1; base += 64) {
    const int m = min(64, off1 - base);
    if (lane < m) {
      const int2 e = pk[base + lane];
      spk[w][lane] = e;
      const uint4* ac = (const uint4*)(a_colh + (size_t)e.x * DA);
      const float* ar = s_ar[w];
      float dot = 0.f;
#pragma unroll
      for (int k = 0; k < 4; ++k) {
        const uint4 q = ac[k];
        const float* a = ar + k * 8;
        dot += __uint_as_float(q.x << 16) * a[0] +
               __uint_as_float(q.x & 0xffff0000u) * a[1] +
               __uint_as_float(q.y << 16) * a[2] +
               __uint_as_float(q.y & 0xffff0000u) * a[3] +
               __uint_as_float(q.z << 16) * a[4] +
               __uint_as_float(q.z & 0xffff0000u) * a[5] +
               __uint_as_float(q.w << 16) * a[6] +
               __uint_as_float(q.w & 0xffff0000u) * a[7];
      }
      const float l = (dot >= 0.f) ? dot : SLOPE * dot;
      sp[w][lane] = __expf(l);   // same-wave RAW, no barrier needed
    }
    int j = 0;
    for (; j + 8 <= m; j += 8) {
#pragma unroll
      for (int u = 0; u < 8; ++u) {
        const int2 e = spk[w][j + u];
        const float pv = sp[w][j + u];
        const uint xv = xh[(size_t)e.x * 64 + lane];
        const float fx = __uint_as_float(xv << 16);
        const float fy = __uint_as_float(xv & 0xffff0000u);
        const float av = __int_as_float(e.y);
        aax += av * fx; aay += av * fy;
        apx += pv * fx; apy += pv * fy;
        deg += pv;
      }
    }
    for (; j < m; ++j) {
      const int2 e = spk[w][j];
      const float pv = sp[w][j];
      const uint xv = xh[(size_t)e.x * 64 + lane];
      const float fx = __uint_as_float(xv << 16);
      const float fy = __uint_as_float(xv & 0xffff0000u);
      const float av = __int_as_float(e.y);
      aax += av * fx; aay += av * fy;
      apx += pv * fx; apy += pv * fy;
      deg += pv;
    }
  }
  const float inv = 0.5f / (deg + 1e-15f);
  ((float2*)feat)[(size_t)i * 64 + lane] =
      make_float2(0.5f * aax + inv * apx, 0.5f * aay + inv * apy);
}

// ---------------- K7: dense GEMM out = feat @ W_x + b ----------------
__global__ __launch_bounds__(256) void gemm_kernel(
    const float* __restrict__ feat, const float* __restrict__ Wx,
    const float* __restrict__ bx, float* __restrict__ out) {
  __shared__ float fs[16][DIN];
  const int t = threadIdx.x;
  const int row0 = blockIdx.x * 16;
  {
    const float4* fg = (const float4*)(feat + (size_t)row0 * DIN);
    float4* fs4 = (float4*)fs;
    fs4[t] = fg[t];
    fs4[t + 256] = fg[t + 256];
  }
  __syncthreads();

  float acc[16];
#pragma unroll
  for (int r = 0; r < 16; ++r) acc[r] = 0.f;

  for (int k = 0; k < DIN; k += 4) {
    const float w0 = Wx[(k + 0) * DOUT + t];
    const float w1 = Wx[(k + 1) * DOUT + t];
    const float w2 = Wx[(k + 2) * DOUT + t];
    const float w3 = Wx[(k + 3) * DOUT + t];
#pragma unroll
    for (int r = 0; r < 16; ++r) {
      const float4 f = *(const float4*)&fs[r][k];
      acc[r] += f.x * w0 + f.y * w1 + f.z * w2 + f.w * w3;
    }
  }

  const float b = bx[t];
#pragma unroll
  for (int r = 0; r < 16; ++r)
    out[(size_t)(row0 + r) * DOUT + t] = acc[r] + b;
}

extern "C" void kernel_launch(void* const* d_in, const int* in_sizes, int n_in,
                              void* d_out, int out_size, void* d_ws, size_t ws_size,
                              hipStream_t stream) {
  const float* x   = (const float*)d_in[0];
  const int*   row = (const int*)d_in[1];
  const int*   col = (const int*)d_in[2];
  const float* adj = (const float*)d_in[3];
  const float* Wr  = (const float*)d_in[4];
  const float* Wc  = (const float*)d_in[5];
  const float* Wx  = (const float*)d_in[6];
  const float* bx  = (const float*)d_in[7];
  float* out = (float*)d_out;

  const int n = in_sizes[0] / DIN;   // 50000
  const int E = in_sizes[1];         // 1600000
  const int nb = (n + 127) >> BSH;   // 391 coarse buckets

  // Workspace layout (ibuf overlaid on feat: disjoint lifetimes —
  // ibuf: part->csr;  feat: node->gemm)
  int* w4 = (int*)d_ws;
  float* a_row   = (float*)w4;  w4 += (size_t)n * DA;        // 6.4 MB
  float* feat    = (float*)w4;  w4 += (size_t)n * DIN;       // 25.6 MB
  int2*  ibuf    = (int2*)feat;                              // overlay (12.8 MB)
  int*   off     = w4;          w4 += n + 1;
  int*   bcnt    = w4;          w4 += nb;                    // zeroed
  int*   bstart  = w4;          w4 += nb + 1;
  int*   bcursor = w4;          w4 += nb;
  w4 = (int*)(((uintptr_t)w4 + 15) & ~(uintptr_t)15);
  ushort* a_colh = (ushort*)w4; w4 += (size_t)n * DA / 2;    // 3.2 MB
  uint*   xh     = (uint*)w4;   w4 += (size_t)n * DIN / 2;   // 12.8 MB
  int2*   pk     = (int2*)w4;                                // 12.8 MB
  // total ~= 61 MB

  hipMemsetAsync(bcnt, 0, (size_t)nb * sizeof(int), stream);

  proj_kernel<<<n / 8, 256, 0, stream>>>(x, Wr, Wc, a_row, a_colh, (ushort*)xh);
  bhist_kernel<<<(E + BH_CHUNK - 1) / BH_CHUNK, 256, 0, stream>>>(row, bcnt, nb, E);
  bscan_kernel<<<1, 512, 0, stream>>>(bcnt, bstart, bcursor, nb);
  part_kernel<<<(E + PB_CHUNK - 1) / PB_CHUNK, 256, 0, stream>>>(
      row, col, adj, bcursor, ibuf, nb, E);
  csr_kernel<<<nb, 256, 0, stream>>>(bstart, ibuf, off, pk, n, E);
  node_kernel<<<(n + 3) / 4, 256, 0, stream>>>(xh, a_row, a_colh, off, pk, feat, n);
  gemm_kernel<<<n / 16, 256, 0, stream>>>(feat, Wx, bx, out);
}